// Round 2
// baseline (1638.711 us; speedup 1.0000x reference)
//
#include <hip/hip_runtime.h>

#define NBRS 200
#define BATCH 2048
#define FEW 5
#define DMODEL 256
#define DINNER 512
#define LHID 512
#define GDIM 2048   // 4*LHID
#define EDIM 128
#define LNEPS 1e-3f

__device__ __forceinline__ float sigmoidf_(float x) { return 1.f / (1.f + expf(-x)); }

// ---------------------------------------------------------------------------
// Gather + sum of 200 neighbor embedding pairs, float4-vectorized.
// S[n, 0:128] = sum_k emb[conn[n,k,0]], S[n,128:256] = sum_k emb[conn[n,k,1]]
// 256 threads = 4 k-subgroups x 64 lanes; lane covers one float4 of [rel|ent].
// ---------------------------------------------------------------------------
__global__ __launch_bounds__(256) void nbr_sum(const int* __restrict__ conn,
                                               const float* __restrict__ emb,
                                               float* __restrict__ S) {
    int row = blockIdx.x;
    __shared__ int idx[NBRS * 2];
    __shared__ float red[4][256];
    int t = threadIdx.x;
    for (int i = t; i < NBRS * 2; i += 256) idx[i] = conn[row * NBRS * 2 + i];
    __syncthreads();
    int g = t >> 6;       // k-subgroup 0..3
    int r = t & 63;
    int sel = r >> 5;     // 0 = rel, 1 = ent
    int d4 = r & 31;      // float4 index within 128 dims
    float4 acc = make_float4(0.f, 0.f, 0.f, 0.f);
#pragma unroll 5
    for (int k = g; k < NBRS; k += 4) {
        int e = idx[k * 2 + sel];
        float4 v = *(const float4*)(emb + (size_t)e * EDIM + d4 * 4);
        acc.x += v.x; acc.y += v.y; acc.z += v.z; acc.w += v.w;
    }
    *(float4*)&red[g][sel * 128 + d4 * 4] = acc;
    __syncthreads();
    float s = red[0][t] + red[1][t] + red[2][t] + red[3][t];
    S[(size_t)row * 256 + t] = s;
}

// gcn_w (128,256) -> gcn_wT (256,128)
__global__ void transpose_gcnw(const float* __restrict__ W, float* __restrict__ WT) {
    int i = blockIdx.x * 256 + threadIdx.x;  // 128*256
    int d = i >> 8, c = i & 255;
    WT[c * 128 + d] = W[i];
}

// out[row, off+d] = tanh((S[row]·gcn_wT[:,d] + 200*bias[d]) / deg[row])
__global__ __launch_bounds__(128) void gcn_kernel(const float* __restrict__ S,
                                                  const float* __restrict__ deg,
                                                  const float* __restrict__ WT,
                                                  const float* __restrict__ bias,
                                                  float* __restrict__ out, int off) {
    int row = blockIdx.x;
    int d = threadIdx.x;  // 128
    __shared__ float sS[256];
    sS[d] = S[(size_t)row * 256 + d];
    sS[d + 128] = S[(size_t)row * 256 + 128 + d];
    __syncthreads();
    float acc = 0.f;
#pragma unroll 8
    for (int c = 0; c < 256; ++c) acc = fmaf(sS[c], WT[c * 128 + d], acc);
    float v = (acc + 200.f * bias[d]) / deg[row];
    out[(size_t)row * 256 + off + d] = tanhf(v);
}

// ---------------------------------------------------------------------------
// fp32 NT GEMM, double-buffered LDS. C[m,n] = sum_k A[m,k]*B[n,k] (+bias[n])
// (+addm[m,n]) (relu). 256 threads. BK=32. TM in {4,8}, TN=4.
// cfg big: BM=64,BN=128,TM=8 -> 512 blocks for 2048x2048 (2 blocks/CU).
// cfg sup: BM=64,BN=64, TM=4.
// M, N must be multiples of BM, BN; K multiple of BK (guaranteed by caller).
// ---------------------------------------------------------------------------
template <int BM, int BN, int TM, int RELU, int BIAS, int ADD>
__global__ __launch_bounds__(256, 2) void gemm_nt(const float* __restrict__ A, int lda,
                                                  const float* __restrict__ B, int ldb,
                                                  float* __restrict__ C, int ldc,
                                                  const float* __restrict__ bias,
                                                  const float* __restrict__ addm, int ldadd,
                                                  int K) {
    constexpr int BK = 32;
    constexpr int THN = BN / 4;           // threads along n
    constexpr int LA = BM * BK / 1024;    // float4 stage-loads per thread (A)
    constexpr int LB = BN * BK / 1024;    // (B)
    __shared__ float As[2][BK][BM];
    __shared__ float Bs[2][BK][BN];
    const int tid = threadIdx.x;
    const int m0 = blockIdx.y * BM;
    const int n0 = blockIdx.x * BN;
    const int tn = tid % THN;
    const int tm = tid / THN;

    float acc[TM][4];
#pragma unroll
    for (int i = 0; i < TM; i++)
#pragma unroll
        for (int j = 0; j < 4; j++) acc[i][j] = 0.f;

    float4 va[LA], vb[LB];

    auto gload = [&](int k0) {
#pragma unroll
        for (int l = 0; l < LA; ++l) {
            int f = tid + l * 256, r = f >> 3, c = f & 7;
            va[l] = *(const float4*)(A + (size_t)(m0 + r) * lda + k0 + c * 4);
        }
#pragma unroll
        for (int l = 0; l < LB; ++l) {
            int f = tid + l * 256, r = f >> 3, c = f & 7;
            vb[l] = *(const float4*)(B + (size_t)(n0 + r) * ldb + k0 + c * 4);
        }
    };
    auto sstore = [&](int buf) {
#pragma unroll
        for (int l = 0; l < LA; ++l) {
            int f = tid + l * 256, r = f >> 3, c = f & 7;
            As[buf][c * 4 + 0][r] = va[l].x;
            As[buf][c * 4 + 1][r] = va[l].y;
            As[buf][c * 4 + 2][r] = va[l].z;
            As[buf][c * 4 + 3][r] = va[l].w;
        }
#pragma unroll
        for (int l = 0; l < LB; ++l) {
            int f = tid + l * 256, r = f >> 3, c = f & 7;
            Bs[buf][c * 4 + 0][r] = vb[l].x;
            Bs[buf][c * 4 + 1][r] = vb[l].y;
            Bs[buf][c * 4 + 2][r] = vb[l].z;
            Bs[buf][c * 4 + 3][r] = vb[l].w;
        }
    };
    auto compute = [&](int buf) {
#pragma unroll
        for (int kk = 0; kk < BK; ++kk) {
            float4 b0 = *(const float4*)&Bs[buf][kk][tn * 4];
            float4 a0 = *(const float4*)&As[buf][kk][tm * 4];
            float ar[TM];
            ar[0] = a0.x; ar[1] = a0.y; ar[2] = a0.z; ar[3] = a0.w;
            if (TM == 8) {
                float4 a1 = *(const float4*)&As[buf][kk][BM / 2 + tm * 4];
                ar[4] = a1.x; ar[5] = a1.y; ar[6] = a1.z; ar[7] = a1.w;
            }
#pragma unroll
            for (int i = 0; i < TM; i++) {
                acc[i][0] = fmaf(ar[i], b0.x, acc[i][0]);
                acc[i][1] = fmaf(ar[i], b0.y, acc[i][1]);
                acc[i][2] = fmaf(ar[i], b0.z, acc[i][2]);
                acc[i][3] = fmaf(ar[i], b0.w, acc[i][3]);
            }
        }
    };

    const int nt = K / BK;
    gload(0);
    sstore(0);
    __syncthreads();
    int cur = 0;
    for (int t = 0; t < nt; ++t) {
        if (t + 1 < nt) gload((t + 1) * BK);
        compute(cur);
        if (t + 1 < nt) {
            __syncthreads();
            sstore(cur ^ 1);
            __syncthreads();
            cur ^= 1;
        }
    }

#pragma unroll
    for (int i = 0; i < TM; ++i) {
        int mrow = (TM == 8) ? ((i < 4) ? tm * 4 + i : BM / 2 + tm * 4 + i - 4) : tm * 4 + i;
        int gm = m0 + mrow;
        int gn = n0 + tn * 4;
        float4 r = make_float4(acc[i][0], acc[i][1], acc[i][2], acc[i][3]);
        if (BIAS) {
            const float4 bv = *(const float4*)&bias[gn];
            r.x += bv.x; r.y += bv.y; r.z += bv.z; r.w += bv.w;
        }
        if (ADD) {
            const float4 av = *(const float4*)&addm[(size_t)gm * ldadd + gn];
            r.x += av.x; r.y += av.y; r.z += av.z; r.w += av.w;
        }
        if (RELU) {
            r.x = fmaxf(r.x, 0.f); r.y = fmaxf(r.y, 0.f);
            r.z = fmaxf(r.z, 0.f); r.w = fmaxf(r.w, 0.f);
        }
        *(float4*)&C[(size_t)gm * ldc + gn] = r;
    }
}

// Tiny-M GEMM (M=5 support rows): one thread per output.
template <int RELU, int BIAS, int ADD>
__global__ __launch_bounds__(256) void small_nt(const float* __restrict__ A, int lda,
                                                const float* __restrict__ B, int ldb,
                                                float* __restrict__ C, int ldc,
                                                const float* __restrict__ bias,
                                                const float* __restrict__ addm, int ldadd,
                                                int M, int N, int K) {
    int o = blockIdx.x * 256 + threadIdx.x;
    if (o >= M * N) return;
    int m = o / N, n = o % N;
    const float4* a4 = (const float4*)(A + (size_t)m * lda);
    const float4* b4 = (const float4*)(B + (size_t)n * ldb);
    float s = 0.f;
#pragma unroll 8
    for (int k = 0; k < K / 4; ++k) {
        float4 x = a4[k], y = b4[k];
        s += x.x * y.x + x.y * y.y + x.z * y.z + x.w * y.w;
    }
    if (BIAS) s += bias[n];
    if (ADD) s += addm[(size_t)m * ldadd + n];
    if (RELU) s = fmaxf(s, 0.f);
    C[(size_t)m * ldc + n] = s;
}

// LayerNorm with ddof=1 std, one wave per 256-elem row
__global__ __launch_bounds__(256) void ln_kernel(const float* __restrict__ X,
                                                 const float* __restrict__ la,
                                                 const float* __restrict__ lb,
                                                 float* __restrict__ Y, int n) {
    int row = blockIdx.x * 4 + (threadIdx.x >> 6);
    int lane = threadIdx.x & 63;
    if (row >= n) return;
    float4 x = *(const float4*)(X + (size_t)row * 256 + lane * 4);
    float s = x.x + x.y + x.z + x.w;
#pragma unroll
    for (int o = 32; o; o >>= 1) s += __shfl_xor(s, o);
    float mu = s * (1.f / 256.f);
    float d0 = x.x - mu, d1 = x.y - mu, d2 = x.z - mu, d3 = x.w - mu;
    float q = d0 * d0 + d1 * d1 + d2 * d2 + d3 * d3;
#pragma unroll
    for (int o = 32; o; o >>= 1) q += __shfl_xor(q, o);
    float sigma = sqrtf(q * (1.f / 255.f));  // ddof=1
    float inv = 1.f / (sigma + LNEPS);
    float4 a = *(const float4*)(la + lane * 4);
    float4 b = *(const float4*)(lb + lane * 4);
    float4 y = make_float4(d0 * inv * a.x + b.x, d1 * inv * a.y + b.y,
                           d2 * inv * a.z + b.z, d3 * inv * a.w + b.w);
    *(float4*)(Y + (size_t)row * 256 + lane * 4) = y;
}

__global__ void mean5(const float* __restrict__ sg, float* __restrict__ s) {
    int d = threadIdx.x;  // 256
    float v = 0.f;
#pragma unroll
    for (int r = 0; r < FEW; r++) v += sg[r * 256 + d];
    s[d] = v * (1.f / FEW);
}

// svec[j] = s · w_hh[j, 256:512]; bsum[j] = b_ih[j] + b_hh[j]
__global__ __launch_bounds__(256) void svec_bsum(const float* __restrict__ s,
                                                 const float* __restrict__ w_hh,
                                                 const float* __restrict__ b_ih,
                                                 const float* __restrict__ b_hh,
                                                 float* __restrict__ svec,
                                                 float* __restrict__ bsum) {
    int j = blockIdx.x * 4 + (threadIdx.x >> 6);
    int lane = threadIdx.x & 63;
    const float* w = w_hh + (size_t)j * LHID + 256;
    float4 v = ((const float4*)w)[lane];
    float4 sv = ((const float4*)s)[lane];
    float p = v.x * sv.x + v.y * sv.y + v.z * sv.z + v.w * sv.w;
#pragma unroll
    for (int o = 32; o; o >>= 1) p += __shfl_down(p, o);
    if (lane == 0) {
        svec[j] = p;
        bsum[j] = b_ih[j] + b_hh[j];
    }
}

// LSTM gate nonlinearity. G rows are 2048 wide: [i | f | g | o] blocks of 512.
template <int FIRST>
__global__ __launch_bounds__(256) void gates_kernel(const float* __restrict__ G,
                                                    const float* __restrict__ qg,
                                                    float* __restrict__ Cst,
                                                    float* __restrict__ H) {
    int idx = blockIdx.x * 256 + threadIdx.x;  // BATCH*512
    int b = idx >> 9, j = idx & 511;
    const float* g = G + (size_t)b * GDIM;
    float gi = g[j], gf = g[512 + j], gg = g[1024 + j], go = g[1536 + j];
    float cn;
    if (FIRST)
        cn = sigmoidf_(gi) * tanhf(gg);  // c_prev = 0
    else
        cn = sigmoidf_(gf) * Cst[idx] + sigmoidf_(gi) * tanhf(gg);
    Cst[idx] = cn;
    if (j < 256) H[(size_t)b * 256 + j] = qg[(size_t)b * 256 + j] + sigmoidf_(go) * tanhf(cn);
}

__global__ __launch_bounds__(256) void scores_kernel(const float* __restrict__ H,
                                                     const float* __restrict__ s,
                                                     float* __restrict__ out) {
    int row = blockIdx.x * 4 + (threadIdx.x >> 6);
    int lane = threadIdx.x & 63;
    float4 h = *(const float4*)(H + (size_t)row * 256 + lane * 4);
    float4 sv = *(const float4*)(s + lane * 4);
    float p = h.x * sv.x + h.y * sv.y + h.z * sv.z + h.w * sv.w;
#pragma unroll
    for (int o = 32; o; o >>= 1) p += __shfl_down(p, o);
    if (lane == 0) out[row] = p;
}

extern "C" void kernel_launch(void* const* d_in, const int* in_sizes, int n_in,
                              void* d_out, int out_size, void* d_ws, size_t ws_size,
                              hipStream_t stream) {
    const int* qlc = (const int*)d_in[0];
    const float* qld = (const float*)d_in[1];
    const int* qrc = (const int*)d_in[2];
    const float* qrd = (const float*)d_in[3];
    const int* slc = (const int*)d_in[4];
    const float* sld = (const float*)d_in[5];
    const int* src_ = (const int*)d_in[6];
    const float* srd = (const float*)d_in[7];
    const float* emb = (const float*)d_in[8];
    const float* gcn_w = (const float*)d_in[9];
    const float* gcn_b = (const float*)d_in[10];
    const float* w1 = (const float*)d_in[11];
    const float* b1 = (const float*)d_in[12];
    const float* w2 = (const float*)d_in[13];
    const float* b2 = (const float*)d_in[14];
    const float* lna = (const float*)d_in[15];
    const float* lnb = (const float*)d_in[16];
    const float* w_ih = (const float*)d_in[17];
    const float* w_hh = (const float*)d_in[18];
    const float* b_ih = (const float*)d_in[19];
    const float* b_hh = (const float*)d_in[20];
    float* out = (float*)d_out;

    float* ws = (float*)d_ws;
    size_t off = 0;
    auto alloc = [&](size_t n) { float* p = ws + off; off += n; return p; };
    float* gcn_wT = alloc(256 * 128);
    float* S_ql = alloc((size_t)BATCH * 256);
    float* S_qr = alloc((size_t)BATCH * 256);
    float* S_sl = alloc(FEW * 256);
    float* S_sr = alloc(FEW * 256);
    float* qn = alloc((size_t)BATCH * 256);
    float* sn = alloc(FEW * 256);
    float* H1q = alloc((size_t)BATCH * 512);
    float* H1s = alloc(FEW * 512);
    float* preq = alloc((size_t)BATCH * 256);
    float* pres = alloc(FEW * 256);
    float* qg = alloc((size_t)BATCH * 256);
    float* sg = alloc(FEW * 256);
    float* svec = alloc(2048);
    float* bsum = alloc(2048);
    float* sbar = alloc(256);
    float* base = alloc((size_t)BATCH * GDIM);
    float* Gbuf = alloc((size_t)BATCH * GDIM);
    float* Cst = alloc((size_t)BATCH * LHID);
    float* Hst = alloc((size_t)BATCH * 256);
    (void)ws_size;

    transpose_gcnw<<<128, 256, 0, stream>>>(gcn_w, gcn_wT);
    nbr_sum<<<BATCH, 256, 0, stream>>>(qlc, emb, S_ql);
    nbr_sum<<<BATCH, 256, 0, stream>>>(qrc, emb, S_qr);
    nbr_sum<<<FEW, 256, 0, stream>>>(slc, emb, S_sl);
    nbr_sum<<<FEW, 256, 0, stream>>>(src_, emb, S_sr);

    gcn_kernel<<<BATCH, 128, 0, stream>>>(S_ql, qld, gcn_wT, gcn_b, qn, 0);
    gcn_kernel<<<BATCH, 128, 0, stream>>>(S_qr, qrd, gcn_wT, gcn_b, qn, 128);
    gcn_kernel<<<FEW, 128, 0, stream>>>(S_sl, sld, gcn_wT, gcn_b, sn, 0);
    gcn_kernel<<<FEW, 128, 0, stream>>>(S_sr, srd, gcn_wT, gcn_b, sn, 128);

    // support encoder: H1 = relu(X W1^T + b1); pre = H1 W2^T + b2 + X; LN
    gemm_nt<64, 64, 4, 1, 1, 0><<<dim3(DINNER / 64, BATCH / 64), 256, 0, stream>>>(
        qn, 256, w1, 256, H1q, 512, b1, nullptr, 0, 256);
    gemm_nt<64, 64, 4, 0, 1, 1><<<dim3(DMODEL / 64, BATCH / 64), 256, 0, stream>>>(
        H1q, 512, w2, 512, preq, 256, b2, qn, 256, 512);
    small_nt<1, 1, 0><<<(FEW * DINNER + 255) / 256, 256, 0, stream>>>(
        sn, 256, w1, 256, H1s, 512, b1, nullptr, 0, FEW, DINNER, 256);
    small_nt<0, 1, 1><<<(FEW * DMODEL + 255) / 256, 256, 0, stream>>>(
        H1s, 512, w2, 512, pres, 256, b2, sn, 256, FEW, DMODEL, 512);
    ln_kernel<<<BATCH / 4, 256, 0, stream>>>(preq, lna, lnb, qg, BATCH);
    ln_kernel<<<2, 256, 0, stream>>>(pres, lna, lnb, sg, FEW);
    mean5<<<1, 256, 0, stream>>>(sg, sbar);

    svec_bsum<<<GDIM / 4, 256, 0, stream>>>(sbar, w_hh, b_ih, b_hh, svec, bsum);

    // base = qg @ w_ih^T + (b_ih + b_hh)
    gemm_nt<64, 128, 8, 0, 1, 0><<<dim3(GDIM / 128, BATCH / 64), 256, 0, stream>>>(
        qg, 256, w_ih, 256, base, GDIM, bsum, nullptr, 0, 256);

    // step 1: h_r = 0 -> gates directly from base
    gates_kernel<1><<<BATCH * LHID / 256, 256, 0, stream>>>(base, qg, Cst, Hst);
    // steps 2..4: G = base + svec + H @ w_hh[:, :256]^T
    for (int s = 2; s <= 4; s++) {
        gemm_nt<64, 128, 8, 0, 1, 1><<<dim3(GDIM / 128, BATCH / 64), 256, 0, stream>>>(
            Hst, 256, w_hh, 512, Gbuf, GDIM, svec, base, GDIM, 256);
        gates_kernel<0><<<BATCH * LHID / 256, 256, 0, stream>>>(Gbuf, qg, Cst, Hst);
    }

    scores_kernel<<<BATCH / 4, 256, 0, stream>>>(Hst, sbar, out);
}

// Round 3
// 631.968 us; speedup vs baseline: 2.5930x; 2.5930x over previous
//
#include <hip/hip_runtime.h>

#define NBRS 200
#define BATCH 2048
#define FEW 5
#define DMODEL 256
#define DINNER 512
#define LHID 512
#define GDIM 2048   // 4*LHID
#define EDIM 128
#define LNEPS 1e-3f

__device__ __forceinline__ float sigmoidf_(float x) { return 1.f / (1.f + expf(-x)); }

// ---------------------------------------------------------------------------
// Gather + sum of 200 neighbor embedding pairs, float4-vectorized.
// ---------------------------------------------------------------------------
__global__ __launch_bounds__(256) void nbr_sum(const int* __restrict__ conn,
                                               const float* __restrict__ emb,
                                               float* __restrict__ S) {
    int row = blockIdx.x;
    __shared__ int idx[NBRS * 2];
    __shared__ float red[4][256];
    int t = threadIdx.x;
    for (int i = t; i < NBRS * 2; i += 256) idx[i] = conn[row * NBRS * 2 + i];
    __syncthreads();
    int g = t >> 6;       // k-subgroup 0..3
    int r = t & 63;
    int sel = r >> 5;     // 0 = rel, 1 = ent
    int d4 = r & 31;      // float4 index within 128 dims
    float4 acc = make_float4(0.f, 0.f, 0.f, 0.f);
#pragma unroll 5
    for (int k = g; k < NBRS; k += 4) {
        int e = idx[k * 2 + sel];
        float4 v = *(const float4*)(emb + (size_t)e * EDIM + d4 * 4);
        acc.x += v.x; acc.y += v.y; acc.z += v.z; acc.w += v.w;
    }
    *(float4*)&red[g][sel * 128 + d4 * 4] = acc;
    __syncthreads();
    float s = red[0][t] + red[1][t] + red[2][t] + red[3][t];
    S[(size_t)row * 256 + t] = s;
}

// gcn_w (128,256) -> gcn_wT (256,128)
__global__ void transpose_gcnw(const float* __restrict__ W, float* __restrict__ WT) {
    int i = blockIdx.x * 256 + threadIdx.x;  // 128*256
    int d = i >> 8, c = i & 255;
    WT[c * 128 + d] = W[i];
}

// out[row, off+d] = tanh((S[row]·gcn_wT[:,d] + 200*bias[d]) / deg[row])
__global__ __launch_bounds__(128) void gcn_kernel(const float* __restrict__ S,
                                                  const float* __restrict__ deg,
                                                  const float* __restrict__ WT,
                                                  const float* __restrict__ bias,
                                                  float* __restrict__ out, int off) {
    int row = blockIdx.x;
    int d = threadIdx.x;  // 128
    __shared__ float sS[256];
    sS[d] = S[(size_t)row * 256 + d];
    sS[d + 128] = S[(size_t)row * 256 + 128 + d];
    __syncthreads();
    float acc = 0.f;
#pragma unroll 8
    for (int c = 0; c < 256; ++c) acc = fmaf(sS[c], WT[c * 128 + d], acc);
    float v = (acc + 200.f * bias[d]) / deg[row];
    out[(size_t)row * 256 + off + d] = tanhf(v);
}

// ---------------------------------------------------------------------------
// fp32 NT GEMM, R1-proven single-buffered structure, 64x64 tile for occupancy.
// C[m,n] = sum_k A[m,k]*B[n,k] (+bias[n]) (+addm[m,n]) (relu).
// 256 threads, BK=32, 4x4 micro-tile, LDS stride 65 (bank-conflict pad).
// M,N multiples of 64; K multiple of 32.
// ---------------------------------------------------------------------------
template <int RELU, int BIAS, int ADD>
__global__ __launch_bounds__(256) void gemm64(const float* __restrict__ A, int lda,
                                              const float* __restrict__ B, int ldb,
                                              float* __restrict__ C, int ldc,
                                              const float* __restrict__ bias,
                                              const float* __restrict__ addm, int ldadd,
                                              int K) {
    constexpr int BK = 32;
    __shared__ float As[BK][65];
    __shared__ float Bs[BK][65];
    const int tid = threadIdx.x;
    const int m0 = blockIdx.y * 64;
    const int n0 = blockIdx.x * 64;
    const int tn = tid & 15;         // 0..15
    const int tm = tid >> 4;         // 0..15
    const int r = tid >> 2;          // stage row 0..63
    const int c8 = (tid & 3) * 8;    // stage col {0,8,16,24}

    float acc[4][4];
#pragma unroll
    for (int i = 0; i < 4; i++)
#pragma unroll
        for (int j = 0; j < 4; j++) acc[i][j] = 0.f;

    const int nt = K / BK;
    for (int t = 0; t < nt; ++t) {
        const int k0 = t * BK;
        const float* pa = A + (size_t)(m0 + r) * lda + k0 + c8;
        float4 a0 = *(const float4*)pa;
        float4 a1 = *(const float4*)(pa + 4);
        const float* pb = B + (size_t)(n0 + r) * ldb + k0 + c8;
        float4 b0 = *(const float4*)pb;
        float4 b1 = *(const float4*)(pb + 4);
        if (t) __syncthreads();
        As[c8 + 0][r] = a0.x; As[c8 + 1][r] = a0.y; As[c8 + 2][r] = a0.z; As[c8 + 3][r] = a0.w;
        As[c8 + 4][r] = a1.x; As[c8 + 5][r] = a1.y; As[c8 + 6][r] = a1.z; As[c8 + 7][r] = a1.w;
        Bs[c8 + 0][r] = b0.x; Bs[c8 + 1][r] = b0.y; Bs[c8 + 2][r] = b0.z; Bs[c8 + 3][r] = b0.w;
        Bs[c8 + 4][r] = b1.x; Bs[c8 + 5][r] = b1.y; Bs[c8 + 6][r] = b1.z; Bs[c8 + 7][r] = b1.w;
        __syncthreads();
#pragma unroll
        for (int kk = 0; kk < BK; ++kk) {
            const float4 av = *(const float4*)&As[kk][tm * 4];
            const float4 bv = *(const float4*)&Bs[kk][tn * 4];
            float ar[4] = {av.x, av.y, av.z, av.w};
            float br[4] = {bv.x, bv.y, bv.z, bv.w};
#pragma unroll
            for (int i = 0; i < 4; i++)
#pragma unroll
                for (int j = 0; j < 4; j++) acc[i][j] = fmaf(ar[i], br[j], acc[i][j]);
        }
    }

#pragma unroll
    for (int i = 0; i < 4; ++i) {
        int gm = m0 + tm * 4 + i;
        int gn = n0 + tn * 4;
        float4 v = make_float4(acc[i][0], acc[i][1], acc[i][2], acc[i][3]);
        if (BIAS) {
            const float4 bv = *(const float4*)&bias[gn];
            v.x += bv.x; v.y += bv.y; v.z += bv.z; v.w += bv.w;
        }
        if (ADD) {
            const float4 av = *(const float4*)&addm[(size_t)gm * ldadd + gn];
            v.x += av.x; v.y += av.y; v.z += av.z; v.w += av.w;
        }
        if (RELU) {
            v.x = fmaxf(v.x, 0.f); v.y = fmaxf(v.y, 0.f);
            v.z = fmaxf(v.z, 0.f); v.w = fmaxf(v.w, 0.f);
        }
        *(float4*)&C[(size_t)gm * ldc + gn] = v;
    }
}

// Tiny-M GEMM (M=5 support rows): one thread per output.
template <int RELU, int BIAS, int ADD>
__global__ __launch_bounds__(256) void small_nt(const float* __restrict__ A, int lda,
                                                const float* __restrict__ B, int ldb,
                                                float* __restrict__ C, int ldc,
                                                const float* __restrict__ bias,
                                                const float* __restrict__ addm, int ldadd,
                                                int M, int N, int K) {
    int o = blockIdx.x * 256 + threadIdx.x;
    if (o >= M * N) return;
    int m = o / N, n = o % N;
    const float4* a4 = (const float4*)(A + (size_t)m * lda);
    const float4* b4 = (const float4*)(B + (size_t)n * ldb);
    float s = 0.f;
#pragma unroll 8
    for (int k = 0; k < K / 4; ++k) {
        float4 x = a4[k], y = b4[k];
        s += x.x * y.x + x.y * y.y + x.z * y.z + x.w * y.w;
    }
    if (BIAS) s += bias[n];
    if (ADD) s += addm[(size_t)m * ldadd + n];
    if (RELU) s = fmaxf(s, 0.f);
    C[(size_t)m * ldc + n] = s;
}

// LayerNorm with ddof=1 std, one wave per 256-elem row
__global__ __launch_bounds__(256) void ln_kernel(const float* __restrict__ X,
                                                 const float* __restrict__ la,
                                                 const float* __restrict__ lb,
                                                 float* __restrict__ Y, int n) {
    int row = blockIdx.x * 4 + (threadIdx.x >> 6);
    int lane = threadIdx.x & 63;
    if (row >= n) return;
    float4 x = *(const float4*)(X + (size_t)row * 256 + lane * 4);
    float s = x.x + x.y + x.z + x.w;
#pragma unroll
    for (int o = 32; o; o >>= 1) s += __shfl_xor(s, o);
    float mu = s * (1.f / 256.f);
    float d0 = x.x - mu, d1 = x.y - mu, d2 = x.z - mu, d3 = x.w - mu;
    float q = d0 * d0 + d1 * d1 + d2 * d2 + d3 * d3;
#pragma unroll
    for (int o = 32; o; o >>= 1) q += __shfl_xor(q, o);
    float sigma = sqrtf(q * (1.f / 255.f));  // ddof=1
    float inv = 1.f / (sigma + LNEPS);
    float4 a = *(const float4*)(la + lane * 4);
    float4 b = *(const float4*)(lb + lane * 4);
    float4 y = make_float4(d0 * inv * a.x + b.x, d1 * inv * a.y + b.y,
                           d2 * inv * a.z + b.z, d3 * inv * a.w + b.w);
    *(float4*)(Y + (size_t)row * 256 + lane * 4) = y;
}

__global__ void mean5(const float* __restrict__ sg, float* __restrict__ s) {
    int d = threadIdx.x;  // 256
    float v = 0.f;
#pragma unroll
    for (int r = 0; r < FEW; r++) v += sg[r * 256 + d];
    s[d] = v * (1.f / FEW);
}

// svec[j] = s · w_hh[j, 256:512]; bsum[j] = b_ih[j] + b_hh[j]
__global__ __launch_bounds__(256) void svec_bsum(const float* __restrict__ s,
                                                 const float* __restrict__ w_hh,
                                                 const float* __restrict__ b_ih,
                                                 const float* __restrict__ b_hh,
                                                 float* __restrict__ svec,
                                                 float* __restrict__ bsum) {
    int j = blockIdx.x * 4 + (threadIdx.x >> 6);
    int lane = threadIdx.x & 63;
    const float* w = w_hh + (size_t)j * LHID + 256;
    float4 v = ((const float4*)w)[lane];
    float4 sv = ((const float4*)s)[lane];
    float p = v.x * sv.x + v.y * sv.y + v.z * sv.z + v.w * sv.w;
#pragma unroll
    for (int o = 32; o; o >>= 1) p += __shfl_down(p, o);
    if (lane == 0) {
        svec[j] = p;
        bsum[j] = b_ih[j] + b_hh[j];
    }
}

// LSTM gate nonlinearity. G rows are 2048 wide: [i | f | g | o] blocks of 512.
template <int FIRST>
__global__ __launch_bounds__(256) void gates_kernel(const float* __restrict__ G,
                                                    const float* __restrict__ qg,
                                                    float* __restrict__ Cst,
                                                    float* __restrict__ H) {
    int idx = blockIdx.x * 256 + threadIdx.x;  // BATCH*512
    int b = idx >> 9, j = idx & 511;
    const float* g = G + (size_t)b * GDIM;
    float gi = g[j], gf = g[512 + j], gg = g[1024 + j], go = g[1536 + j];
    float cn;
    if (FIRST)
        cn = sigmoidf_(gi) * tanhf(gg);  // c_prev = 0
    else
        cn = sigmoidf_(gf) * Cst[idx] + sigmoidf_(gi) * tanhf(gg);
    Cst[idx] = cn;
    if (j < 256) H[(size_t)b * 256 + j] = qg[(size_t)b * 256 + j] + sigmoidf_(go) * tanhf(cn);
}

__global__ __launch_bounds__(256) void scores_kernel(const float* __restrict__ H,
                                                     const float* __restrict__ s,
                                                     float* __restrict__ out) {
    int row = blockIdx.x * 4 + (threadIdx.x >> 6);
    int lane = threadIdx.x & 63;
    float4 h = *(const float4*)(H + (size_t)row * 256 + lane * 4);
    float4 sv = *(const float4*)(s + lane * 4);
    float p = h.x * sv.x + h.y * sv.y + h.z * sv.z + h.w * sv.w;
#pragma unroll
    for (int o = 32; o; o >>= 1) p += __shfl_down(p, o);
    if (lane == 0) out[row] = p;
}

extern "C" void kernel_launch(void* const* d_in, const int* in_sizes, int n_in,
                              void* d_out, int out_size, void* d_ws, size_t ws_size,
                              hipStream_t stream) {
    const int* qlc = (const int*)d_in[0];
    const float* qld = (const float*)d_in[1];
    const int* qrc = (const int*)d_in[2];
    const float* qrd = (const float*)d_in[3];
    const int* slc = (const int*)d_in[4];
    const float* sld = (const float*)d_in[5];
    const int* src_ = (const int*)d_in[6];
    const float* srd = (const float*)d_in[7];
    const float* emb = (const float*)d_in[8];
    const float* gcn_w = (const float*)d_in[9];
    const float* gcn_b = (const float*)d_in[10];
    const float* w1 = (const float*)d_in[11];
    const float* b1 = (const float*)d_in[12];
    const float* w2 = (const float*)d_in[13];
    const float* b2 = (const float*)d_in[14];
    const float* lna = (const float*)d_in[15];
    const float* lnb = (const float*)d_in[16];
    const float* w_ih = (const float*)d_in[17];
    const float* w_hh = (const float*)d_in[18];
    const float* b_ih = (const float*)d_in[19];
    const float* b_hh = (const float*)d_in[20];
    float* out = (float*)d_out;

    float* ws = (float*)d_ws;
    size_t off = 0;
    auto alloc = [&](size_t n) { float* p = ws + off; off += n; return p; };
    float* gcn_wT = alloc(256 * 128);
    float* S_ql = alloc((size_t)BATCH * 256);
    float* S_qr = alloc((size_t)BATCH * 256);
    float* S_sl = alloc(FEW * 256);
    float* S_sr = alloc(FEW * 256);
    float* qn = alloc((size_t)BATCH * 256);
    float* sn = alloc(FEW * 256);
    float* H1q = alloc((size_t)BATCH * 512);
    float* H1s = alloc(FEW * 512);
    float* preq = alloc((size_t)BATCH * 256);
    float* pres = alloc(FEW * 256);
    float* qg = alloc((size_t)BATCH * 256);
    float* sg = alloc(FEW * 256);
    float* svec = alloc(2048);
    float* bsum = alloc(2048);
    float* sbar = alloc(256);
    float* base = alloc((size_t)BATCH * GDIM);
    float* Gbuf = alloc((size_t)BATCH * GDIM);
    float* Cst = alloc((size_t)BATCH * LHID);
    float* Hst = alloc((size_t)BATCH * 256);
    (void)ws_size;

    transpose_gcnw<<<128, 256, 0, stream>>>(gcn_w, gcn_wT);
    nbr_sum<<<BATCH, 256, 0, stream>>>(qlc, emb, S_ql);
    nbr_sum<<<BATCH, 256, 0, stream>>>(qrc, emb, S_qr);
    nbr_sum<<<FEW, 256, 0, stream>>>(slc, emb, S_sl);
    nbr_sum<<<FEW, 256, 0, stream>>>(src_, emb, S_sr);

    gcn_kernel<<<BATCH, 128, 0, stream>>>(S_ql, qld, gcn_wT, gcn_b, qn, 0);
    gcn_kernel<<<BATCH, 128, 0, stream>>>(S_qr, qrd, gcn_wT, gcn_b, qn, 128);
    gcn_kernel<<<FEW, 128, 0, stream>>>(S_sl, sld, gcn_wT, gcn_b, sn, 0);
    gcn_kernel<<<FEW, 128, 0, stream>>>(S_sr, srd, gcn_wT, gcn_b, sn, 128);

    // support encoder: H1 = relu(X W1^T + b1); pre = H1 W2^T + b2 + X; LN
    gemm64<1, 1, 0><<<dim3(DINNER / 64, BATCH / 64), 256, 0, stream>>>(
        qn, 256, w1, 256, H1q, 512, b1, nullptr, 0, 256);
    gemm64<0, 1, 1><<<dim3(DMODEL / 64, BATCH / 64), 256, 0, stream>>>(
        H1q, 512, w2, 512, preq, 256, b2, qn, 256, 512);
    small_nt<1, 1, 0><<<(FEW * DINNER + 255) / 256, 256, 0, stream>>>(
        sn, 256, w1, 256, H1s, 512, b1, nullptr, 0, FEW, DINNER, 256);
    small_nt<0, 1, 1><<<(FEW * DMODEL + 255) / 256, 256, 0, stream>>>(
        H1s, 512, w2, 512, pres, 256, b2, sn, 256, FEW, DMODEL, 512);
    ln_kernel<<<BATCH / 4, 256, 0, stream>>>(preq, lna, lnb, qg, BATCH);
    ln_kernel<<<2, 256, 0, stream>>>(pres, lna, lnb, sg, FEW);
    mean5<<<1, 256, 0, stream>>>(sg, sbar);

    svec_bsum<<<GDIM / 4, 256, 0, stream>>>(sbar, w_hh, b_ih, b_hh, svec, bsum);

    // base = qg @ w_ih^T + (b_ih + b_hh)
    gemm64<0, 1, 0><<<dim3(GDIM / 64, BATCH / 64), 256, 0, stream>>>(
        qg, 256, w_ih, 256, base, GDIM, bsum, nullptr, 0, 256);

    // step 1: h_r = 0 -> gates directly from base
    gates_kernel<1><<<BATCH * LHID / 256, 256, 0, stream>>>(base, qg, Cst, Hst);
    // steps 2..4: G = base + svec + H @ w_hh[:, :256]^T
    for (int s = 2; s <= 4; s++) {
        gemm64<0, 1, 1><<<dim3(GDIM / 64, BATCH / 64), 256, 0, stream>>>(
            Hst, 256, w_hh, 512, Gbuf, GDIM, svec, base, GDIM, 256);
        gates_kernel<0><<<BATCH * LHID / 256, 256, 0, stream>>>(Gbuf, qg, Cst, Hst);
    }

    scores_kernel<<<BATCH / 4, 256, 0, stream>>>(Hst, sbar, out);
}

// Round 7
// 568.930 us; speedup vs baseline: 2.8803x; 1.1108x over previous
//
#include <hip/hip_runtime.h>

#define NBRS 200
#define BATCH 2048
#define FEW 5
#define DMODEL 256
#define DINNER 512
#define LHID 512
#define GDIM 2048   // 4*LHID
#define EDIM 128
#define LNEPS 1e-3f

__device__ __forceinline__ float sigmoidf_(float x) { return 1.f / (1.f + expf(-x)); }

// ---------------------------------------------------------------------------
// Fused gather + sum + GCN matvec + tanh for all 4 connection tables.
// Block b -> (table, row). Per block: S = sum of 200 [rel|ent] embedding rows
// (256 floats, LDS), then out[row, off+d] = tanh((S . W[d,:] + 200*b[d]) / deg).
// ---------------------------------------------------------------------------
__global__ __launch_bounds__(256) void nbr_gcn(
    const int* __restrict__ qlc, const float* __restrict__ qld,
    const int* __restrict__ qrc, const float* __restrict__ qrd,
    const int* __restrict__ slc, const float* __restrict__ sld,
    const int* __restrict__ src_, const float* __restrict__ srd,
    const float* __restrict__ emb, const float* __restrict__ WT,
    const float* __restrict__ bias, float* __restrict__ qn, float* __restrict__ sn) {
    __shared__ int idx[NBRS * 2];
    __shared__ float red[4][256];
    __shared__ float sS[256];
    __shared__ float part[256];

    int b = blockIdx.x;
    const int* conn; const float* deg; float* outp; int off, row;
    if (b < 2048)      { conn = qlc;  deg = qld; outp = qn; off = 0;   row = b; }
    else if (b < 4096) { conn = qrc;  deg = qrd; outp = qn; off = 128; row = b - 2048; }
    else if (b < 4101) { conn = slc;  deg = sld; outp = sn; off = 0;   row = b - 4096; }
    else               { conn = src_; deg = srd; outp = sn; off = 128; row = b - 4101; }

    int t = threadIdx.x;
    for (int i = t; i < NBRS * 2; i += 256) idx[i] = conn[row * NBRS * 2 + i];
    __syncthreads();

    int g = t >> 6;       // k-subgroup 0..3
    int r = t & 63;
    int sel = r >> 5;     // 0 = rel, 1 = ent
    int d4 = r & 31;      // float4 index within 128 dims
    float4 acc = make_float4(0.f, 0.f, 0.f, 0.f);
#pragma unroll 5
    for (int k = g; k < NBRS; k += 4) {
        int e = idx[k * 2 + sel];
        float4 v = *(const float4*)(emb + (size_t)e * EDIM + d4 * 4);
        acc.x += v.x; acc.y += v.y; acc.z += v.z; acc.w += v.w;
    }
    *(float4*)&red[g][sel * 128 + d4 * 4] = acc;
    __syncthreads();
    sS[t] = red[0][t] + red[1][t] + red[2][t] + red[3][t];
    __syncthreads();

    // matvec: 2 threads per output dim d, each covers 128 of the 256 c's
    int d = t & 127;
    int half = t >> 7;
    float a = 0.f;
    const float* w = WT + (size_t)(half * 128) * 128 + d;
    const float* s = sS + half * 128;
#pragma unroll 8
    for (int c = 0; c < 128; ++c) a = fmaf(s[c], w[(size_t)c * 128], a);
    part[t] = a;
    __syncthreads();
    if (t < 128) {
        float v = (part[t] + part[t + 128] + 200.f * bias[t]) / deg[row];
        outp[(size_t)row * 256 + off + t] = tanhf(v);
    }
}

// gcn_w (128,256) -> gcn_wT (256,128)
__global__ void transpose_gcnw(const float* __restrict__ W, float* __restrict__ WT) {
    int i = blockIdx.x * 256 + threadIdx.x;  // 128*256
    int d = i >> 8, c = i & 255;
    WT[c * 128 + d] = W[i];
}

// ---------------------------------------------------------------------------
// fp32 NT GEMM, single-buffered LDS + register prefetch of next K-tile.
// C[m,n] = sum_k A[m,k]*B[n,k] (+bias[n]) (+addm[m,n]) (relu).
// 256 threads, 64x64 tile, BK=32, 4x4 micro, LDS stride 65.
// M,N multiples of 64; K multiple of 32.
// ---------------------------------------------------------------------------
template <int RELU, int BIAS, int ADD>
__global__ __launch_bounds__(256) void gemm64(const float* __restrict__ A, int lda,
                                              const float* __restrict__ B, int ldb,
                                              float* __restrict__ C, int ldc,
                                              const float* __restrict__ bias,
                                              const float* __restrict__ addm, int ldadd,
                                              int K) {
    constexpr int BK = 32;
    __shared__ float As[BK][65];
    __shared__ float Bs[BK][65];
    const int tid = threadIdx.x;
    const int m0 = blockIdx.y * 64;
    const int n0 = blockIdx.x * 64;
    const int tn = tid & 15;         // 0..15
    const int tm = tid >> 4;         // 0..15
    const int r = tid >> 2;          // stage row 0..63
    const int c8 = (tid & 3) * 8;    // stage col {0,8,16,24}

    float acc[4][4];
#pragma unroll
    for (int i = 0; i < 4; i++)
#pragma unroll
        for (int j = 0; j < 4; j++) acc[i][j] = 0.f;

    const float* pa = A + (size_t)(m0 + r) * lda + c8;
    const float* pb = B + (size_t)(n0 + r) * ldb + c8;
    float4 a0 = *(const float4*)pa;
    float4 a1 = *(const float4*)(pa + 4);
    float4 b0 = *(const float4*)pb;
    float4 b1 = *(const float4*)(pb + 4);

    const int nt = K / BK;
    for (int t = 0; t < nt; ++t) {
        if (t) __syncthreads();
        As[c8 + 0][r] = a0.x; As[c8 + 1][r] = a0.y; As[c8 + 2][r] = a0.z; As[c8 + 3][r] = a0.w;
        As[c8 + 4][r] = a1.x; As[c8 + 5][r] = a1.y; As[c8 + 6][r] = a1.z; As[c8 + 7][r] = a1.w;
        Bs[c8 + 0][r] = b0.x; Bs[c8 + 1][r] = b0.y; Bs[c8 + 2][r] = b0.z; Bs[c8 + 3][r] = b0.w;
        Bs[c8 + 4][r] = b1.x; Bs[c8 + 5][r] = b1.y; Bs[c8 + 6][r] = b1.z; Bs[c8 + 7][r] = b1.w;
        __syncthreads();
        if (t + 1 < nt) {  // issue next-tile loads; latency hides under compute
            const float* qa = pa + (t + 1) * BK;
            const float* qb = pb + (t + 1) * BK;
            a0 = *(const float4*)qa;
            a1 = *(const float4*)(qa + 4);
            b0 = *(const float4*)qb;
            b1 = *(const float4*)(qb + 4);
        }
#pragma unroll
        for (int kk = 0; kk < BK; ++kk) {
            const float4 av = *(const float4*)&As[kk][tm * 4];
            const float4 bv = *(const float4*)&Bs[kk][tn * 4];
            float ar[4] = {av.x, av.y, av.z, av.w};
            float br[4] = {bv.x, bv.y, bv.z, bv.w};
#pragma unroll
            for (int i = 0; i < 4; i++)
#pragma unroll
                for (int j = 0; j < 4; j++) acc[i][j] = fmaf(ar[i], br[j], acc[i][j]);
        }
    }

#pragma unroll
    for (int i = 0; i < 4; ++i) {
        int gm = m0 + tm * 4 + i;
        int gn = n0 + tn * 4;
        float4 v = make_float4(acc[i][0], acc[i][1], acc[i][2], acc[i][3]);
        if (BIAS) {
            const float4 bv = *(const float4*)&bias[gn];
            v.x += bv.x; v.y += bv.y; v.z += bv.z; v.w += bv.w;
        }
        if (ADD) {
            const float4 av = *(const float4*)&addm[(size_t)gm * ldadd + gn];
            v.x += av.x; v.y += av.y; v.z += av.z; v.w += av.w;
        }
        if (RELU) {
            v.x = fmaxf(v.x, 0.f); v.y = fmaxf(v.y, 0.f);
            v.z = fmaxf(v.z, 0.f); v.w = fmaxf(v.w, 0.f);
        }
        *(float4*)&C[(size_t)gm * ldc + gn] = v;
    }
}

// Tiny-M GEMM (M=5 support rows): one thread per output.
template <int RELU, int BIAS, int ADD>
__global__ __launch_bounds__(256) void small_nt(const float* __restrict__ A, int lda,
                                                const float* __restrict__ B, int ldb,
                                                float* __restrict__ C, int ldc,
                                                const float* __restrict__ bias,
                                                const float* __restrict__ addm, int ldadd,
                                                int M, int N, int K) {
    int o = blockIdx.x * 256 + threadIdx.x;
    if (o >= M * N) return;
    int m = o / N, n = o % N;
    const float4* a4 = (const float4*)(A + (size_t)m * lda);
    const float4* b4 = (const float4*)(B + (size_t)n * ldb);
    float s = 0.f;
#pragma unroll 8
    for (int k = 0; k < K / 4; ++k) {
        float4 x = a4[k], y = b4[k];
        s += x.x * y.x + x.y * y.y + x.z * y.z + x.w * y.w;
    }
    if (BIAS) s += bias[n];
    if (ADD) s += addm[(size_t)m * ldadd + n];
    if (RELU) s = fmaxf(s, 0.f);
    C[(size_t)m * ldc + n] = s;
}

// LayerNorm with ddof=1 std, one wave per 256-elem row
__global__ __launch_bounds__(256) void ln_kernel(const float* __restrict__ X,
                                                 const float* __restrict__ la,
                                                 const float* __restrict__ lb,
                                                 float* __restrict__ Y, int n) {
    int row = blockIdx.x * 4 + (threadIdx.x >> 6);
    int lane = threadIdx.x & 63;
    if (row >= n) return;
    float4 x = *(const float4*)(X + (size_t)row * 256 + lane * 4);
    float s = x.x + x.y + x.z + x.w;
#pragma unroll
    for (int o = 32; o; o >>= 1) s += __shfl_xor(s, o);
    float mu = s * (1.f / 256.f);
    float d0 = x.x - mu, d1 = x.y - mu, d2 = x.z - mu, d3 = x.w - mu;
    float q = d0 * d0 + d1 * d1 + d2 * d2 + d3 * d3;
#pragma unroll
    for (int o = 32; o; o >>= 1) q += __shfl_xor(q, o);
    float sigma = sqrtf(q * (1.f / 255.f));  // ddof=1
    float inv = 1.f / (sigma + LNEPS);
    float4 a = *(const float4*)(la + lane * 4);
    float4 b = *(const float4*)(lb + lane * 4);
    float4 y = make_float4(d0 * inv * a.x + b.x, d1 * inv * a.y + b.y,
                           d2 * inv * a.z + b.z, d3 * inv * a.w + b.w);
    *(float4*)(Y + (size_t)row * 256 + lane * 4) = y;
}

__global__ void mean5(const float* __restrict__ sg, float* __restrict__ s) {
    int d = threadIdx.x;  // 256
    float v = 0.f;
#pragma unroll
    for (int r = 0; r < FEW; r++) v += sg[r * 256 + d];
    s[d] = v * (1.f / FEW);
}

// svec[j] = s · w_hh[j, 256:512]; bsum[j] = b_ih[j] + b_hh[j]
__global__ __launch_bounds__(256) void svec_bsum(const float* __restrict__ s,
                                                 const float* __restrict__ w_hh,
                                                 const float* __restrict__ b_ih,
                                                 const float* __restrict__ b_hh,
                                                 float* __restrict__ svec,
                                                 float* __restrict__ bsum) {
    int j = blockIdx.x * 4 + (threadIdx.x >> 6);
    int lane = threadIdx.x & 63;
    const float* w = w_hh + (size_t)j * LHID + 256;
    float4 v = ((const float4*)w)[lane];
    float4 sv = ((const float4*)s)[lane];
    float p = v.x * sv.x + v.y * sv.y + v.z * sv.z + v.w * sv.w;
#pragma unroll
    for (int o = 32; o; o >>= 1) p += __shfl_down(p, o);
    if (lane == 0) {
        svec[j] = p;
        bsum[j] = b_ih[j] + b_hh[j];
    }
}

// LSTM gate nonlinearity. G rows are 2048 wide: [i | f | g | o] blocks of 512.
template <int FIRST>
__global__ __launch_bounds__(256) void gates_kernel(const float* __restrict__ G,
                                                    const float* __restrict__ qg,
                                                    float* __restrict__ Cst,
                                                    float* __restrict__ H) {
    int idx = blockIdx.x * 256 + threadIdx.x;  // BATCH*512
    int b = idx >> 9, j = idx & 511;
    const float* g = G + (size_t)b * GDIM;
    float gi = g[j], gf = g[512 + j], gg = g[1024 + j], go = g[1536 + j];
    float cn;
    if (FIRST)
        cn = sigmoidf_(gi) * tanhf(gg);  // c_prev = 0
    else
        cn = sigmoidf_(gf) * Cst[idx] + sigmoidf_(gi) * tanhf(gg);
    Cst[idx] = cn;
    if (j < 256) H[(size_t)b * 256 + j] = qg[(size_t)b * 256 + j] + sigmoidf_(go) * tanhf(cn);
}

__global__ __launch_bounds__(256) void scores_kernel(const float* __restrict__ H,
                                                     const float* __restrict__ s,
                                                     float* __restrict__ out) {
    int row = blockIdx.x * 4 + (threadIdx.x >> 6);
    int lane = threadIdx.x & 63;
    float4 h = *(const float4*)(H + (size_t)row * 256 + lane * 4);
    float4 sv = *(const float4*)(s + lane * 4);
    float p = h.x * sv.x + h.y * sv.y + h.z * sv.z + h.w * sv.w;
#pragma unroll
    for (int o = 32; o; o >>= 1) p += __shfl_down(p, o);
    if (lane == 0) out[row] = p;
}

extern "C" void kernel_launch(void* const* d_in, const int* in_sizes, int n_in,
                              void* d_out, int out_size, void* d_ws, size_t ws_size,
                              hipStream_t stream) {
    const int* qlc = (const int*)d_in[0];
    const float* qld = (const float*)d_in[1];
    const int* qrc = (const int*)d_in[2];
    const float* qrd = (const float*)d_in[3];
    const int* slc = (const int*)d_in[4];
    const float* sld = (const float*)d_in[5];
    const int* src_ = (const int*)d_in[6];
    const float* srd = (const float*)d_in[7];
    const float* emb = (const float*)d_in[8];
    const float* gcn_w = (const float*)d_in[9];
    const float* gcn_b = (const float*)d_in[10];
    const float* w1 = (const float*)d_in[11];
    const float* b1 = (const float*)d_in[12];
    const float* w2 = (const float*)d_in[13];
    const float* b2 = (const float*)d_in[14];
    const float* lna = (const float*)d_in[15];
    const float* lnb = (const float*)d_in[16];
    const float* w_ih = (const float*)d_in[17];
    const float* w_hh = (const float*)d_in[18];
    const float* b_ih = (const float*)d_in[19];
    const float* b_hh = (const float*)d_in[20];
    float* out = (float*)d_out;

    float* ws = (float*)d_ws;
    size_t off = 0;
    auto alloc = [&](size_t n) { float* p = ws + off; off += n; return p; };
    float* gcn_wT = alloc(256 * 128);
    float* qn = alloc((size_t)BATCH * 256);
    float* sn = alloc(FEW * 256);
    float* H1q = alloc((size_t)BATCH * 512);
    float* H1s = alloc(FEW * 512);
    float* preq = alloc((size_t)BATCH * 256);
    float* pres = alloc(FEW * 256);
    float* qg = alloc((size_t)BATCH * 256);
    float* sg = alloc(FEW * 256);
    float* svec = alloc(2048);
    float* bsum = alloc(2048);
    float* sbar = alloc(256);
    float* base = alloc((size_t)BATCH * GDIM);
    float* Gbuf = alloc((size_t)BATCH * GDIM);
    float* Cst = alloc((size_t)BATCH * LHID);
    float* Hst = alloc((size_t)BATCH * 256);
    (void)ws_size;

    transpose_gcnw<<<128, 256, 0, stream>>>(gcn_w, gcn_wT);
    nbr_gcn<<<2 * BATCH + 2 * FEW, 256, 0, stream>>>(qlc, qld, qrc, qrd, slc, sld, src_, srd,
                                                     emb, gcn_wT, gcn_b, qn, sn);

    // support encoder: H1 = relu(X W1^T + b1); pre = H1 W2^T + b2 + X; LN
    gemm64<1, 1, 0><<<dim3(DINNER / 64, BATCH / 64), 256, 0, stream>>>(
        qn, 256, w1, 256, H1q, 512, b1, nullptr, 0, 256);
    gemm64<0, 1, 1><<<dim3(DMODEL / 64, BATCH / 64), 256, 0, stream>>>(
        H1q, 512, w2, 512, preq, 256, b2, qn, 256, 512);
    small_nt<1, 1, 0><<<(FEW * DINNER + 255) / 256, 256, 0, stream>>>(
        sn, 256, w1, 256, H1s, 512, b1, nullptr, 0, FEW, DINNER, 256);
    small_nt<0, 1, 1><<<(FEW * DMODEL + 255) / 256, 256, 0, stream>>>(
        H1s, 512, w2, 512, pres, 256, b2, sn, 256, FEW, DMODEL, 512);
    ln_kernel<<<BATCH / 4, 256, 0, stream>>>(preq, lna, lnb, qg, BATCH);
    ln_kernel<<<2, 256, 0, stream>>>(pres, lna, lnb, sg, FEW);
    mean5<<<1, 256, 0, stream>>>(sg, sbar);

    svec_bsum<<<GDIM / 4, 256, 0, stream>>>(sbar, w_hh, b_ih, b_hh, svec, bsum);

    // base = qg @ w_ih^T + (b_ih + b_hh)
    gemm64<0, 1, 0><<<dim3(GDIM / 64, BATCH / 64), 256, 0, stream>>>(
        qg, 256, w_ih, 256, base, GDIM, bsum, nullptr, 0, 256);

    // step 1: h_r = 0 -> gates directly from base
    gates_kernel<1><<<BATCH * LHID / 256, 256, 0, stream>>>(base, qg, Cst, Hst);
    // steps 2..4: G = base + svec + H @ w_hh[:, :256]^T
    for (int s = 2; s <= 4; s++) {
        gemm64<0, 1, 1><<<dim3(GDIM / 64, BATCH / 64), 256, 0, stream>>>(
            Hst, 256, w_hh, 512, Gbuf, GDIM, svec, base, GDIM, 256);
        gates_kernel<0><<<BATCH * LHID / 256, 256, 0, stream>>>(Gbuf, qg, Cst, Hst);
    }

    scores_kernel<<<BATCH / 4, 256, 0, stream>>>(Hst, sbar, out);
}